// Round 5
// baseline (737.583 us; speedup 1.0000x reference)
//
#include <hip/hip_runtime.h>
#include <hip/hip_bf16.h>

// Problem constants
#define B   16
#define H   24
#define W   96
#define C   1024
#define HID 256
#define V   5000
#define EMB 256
#define HW  (H*W)          // 2304
#define BN_EPS 1e-5f
#define H2  (H+2)          // 26 (halo-padded)
#define W2  (W+2)          // 98

// d_out layout (floats): output[B*V] | hidden[B*HID] | alpha[B*HW] | att_sum[B*HW]
#define OUT0 0
#define OUT1 (B*V)
#define OUT2 (OUT1 + B*HID)
#define OUT3 (OUT2 + B*HW)

// ws layout (bytes, 256-aligned)
#define WSB_IMGT  0                      // B*HW*C bf16      = 75,497,472
#define WSB_ETP   75497472               // B*H2*W2*256 bf16 = 20,873,216
#define WSB_WTB   96370688               // 9*256*256 bf16   =  1,179,648
#define WSB_UAT   97550336               // 256*1024 bf16    =    524,288
#define WSB_E     98074624               // 2*B*HW f32       =    294,912
#define WSB_ST1   98369536               // B*256 f32
#define WSB_CT    98385920               // B*1024 f32
#define WSB_PRE   98451456               // B*128 f32
#define WSB_GIGH1 98459648               // B*1536 f32
#define WSB_ST1G  98557952               // B*256 f32
#define WSB_GH2   98574336               // B*896 f32
#define WSB_GI2   98631680               // 4*B*896 f32
#define WSB_STW   98861056               // B*256 f32

typedef __attribute__((ext_vector_type(8))) short short8;
typedef __attribute__((ext_vector_type(4))) float f32x4;

__device__ inline unsigned short f2bf(float f) {
    union { float f; unsigned int u; } v; v.f = f;
    unsigned int r = v.u + 0x7fffu + ((v.u >> 16) & 1u);   // RNE
    return (unsigned short)(r >> 16);
}
__device__ inline float bf2f(unsigned short u) {
    union { unsigned int u; float f; } v; v.u = ((unsigned int)u) << 16;
    return v.f;
}

// ---------------- img fp32 [b][c][hw] -> bf16 [b][hw][c] (tiled LDS transpose) ----------------
__global__ __launch_bounds__(256) void k_imgT(const float* img, unsigned short* imgT)
{
    int hw0 = blockIdx.x*128, c1 = blockIdx.y*128, b = blockIdx.z;
    int t = threadIdx.x;
    __shared__ unsigned short tr[128*136];                  // [hw][c] pad->136
    #pragma unroll
    for (int i = 0; i < 16; ++i) {
        int flat = i*1024 + t*4;                            // 0..16383
        int r = flat >> 7;                                  // c-row
        int col = flat & 127;                               // hw-col
        float4 v = *(const float4*)&img[((size_t)(b*C + c1 + r))*HW + hw0 + col];
        tr[(col+0)*136 + r] = f2bf(v.x);
        tr[(col+1)*136 + r] = f2bf(v.y);
        tr[(col+2)*136 + r] = f2bf(v.z);
        tr[(col+3)*136 + r] = f2bf(v.w);
    }
    __syncthreads();
    #pragma unroll
    for (int i = 0; i < 8; ++i) {
        int flat = i*2048 + t*8;
        int orow = flat >> 7;                               // hw
        int oc = flat & 127;
        *(short8*)&imgT[((size_t)(b*HW) + hw0 + orow)*1024 + c1 + oc] =
            *(const short8*)&tr[orow*136 + oc];
    }
}

// ---------------- K2: 1-ch 3x3 conv on alpha_t + attention_sum -> att_sum ----------------
__global__ __launch_bounds__(256) void k_attsum(
    const float* att_in, const float* alpha_t, const float* cw, const float* cb,
    float* att_out)
{
    int i = blockIdx.x*256 + threadIdx.x;
    int w = i % W; int h = (i / W) % H; int b = i / HW;
    float s = cb[0];
    #pragma unroll
    for (int kh = 0; kh < 3; ++kh) {
        int r = h + kh - 1; if (r < 0 || r >= H) continue;
        #pragma unroll
        for (int kw = 0; kw < 3; ++kw) {
            int c = w + kw - 1; if (c < 0 || c >= W) continue;
            s += alpha_t[(b*H + r)*W + c]*cw[kh*3+kw];
        }
    }
    att_out[i] = att_in[i] + s;
}

// ---------------- K3: conv_tan_w OIHW -> bf16 [khw][o][c] ----------------
__global__ __launch_bounds__(256) void k_wtb(const float* src, unsigned short* dst)
{
    int idx = blockIdx.x*256 + threadIdx.x;     // 9*256*256
    int c = idx & 255; int o = (idx >> 8) & 255; int khw = idx >> 16;
    dst[(khw*256 + o)*256 + c] = f2bf(src[(o*256 + c)*9 + khw]);
}

// ---------------- K3b: ua_w [c][d] -> bf16 [d][c] ----------------
__global__ __launch_bounds__(256) void k_uat(const float* src, unsigned short* dst)
{
    int idx = blockIdx.x*256 + threadIdx.x;     // 256*1024
    int c = idx & 1023; int d = idx >> 10;
    dst[d*1024 + c] = f2bf(src[c*256 + d]);
}

// ---------------- K3c: zero et_p (incl. halo) ----------------
__global__ __launch_bounds__(256) void k_zero(int4* p)
{
    p[blockIdx.x*256 + threadIdx.x] = make_int4(0,0,0,0);
}

// ---------------- GRU1 matmuls: gigh[b][0:768]=emb@wi, [768:1536]=h0@wh ----------------
__global__ __launch_bounds__(256) void k_tail1(
    const int* y, const float* emb_table, const float* h0,
    const float* wi, const float* wh, float* gigh)
{
    int virt = blockIdx.x*16;            // 0..1535
    int t = threadIdx.x;
    bool gi_mode = virt < 768;
    __shared__ float a_l[16*256];
    for (int i = t; i < 4096; i += 256) {
        int b = i >> 8, k = i & 255;
        a_l[i] = gi_mode ? emb_table[y[b]*EMB + k] : h0[b*HID + k];
    }
    __syncthreads();
    int nl = t & 15, b = t >> 4;
    int n = (gi_mode ? virt : virt - 768) + nl;
    const float* wp = gi_mode ? wi : wh;
    float acc = 0.f;
    #pragma unroll 16
    for (int k = 0; k < 256; ++k) acc += a_l[b*256 + k]*wp[k*768 + n];
    gigh[b*1536 + virt + nl] = acc;
}

// ---------------- GRU1 nonlinearity -> st1g ----------------
__global__ __launch_bounds__(256) void k_comb1(
    const float* gigh, const float* h0, const float* bi, const float* bh, float* st1g)
{
    int b = blockIdx.x, t = threadIdx.x;
    const float* g = gigh + b*1536;
    float ir = g[t] + bi[t], iz = g[256+t] + bi[256+t], in_ = g[512+t] + bi[512+t];
    float hr = g[768+t] + bh[t], hz = g[1024+t] + bh[256+t], hn = g[1280+t] + bh[512+t];
    float r = 1.f/(1.f+__expf(-(ir+hr)));
    float z = 1.f/(1.f+__expf(-(iz+hz)));
    float n = tanhf(in_ + r*hn);
    st1g[b*256+t] = (1.f - z)*n + z*h0[b*HID + t];
}

// ---------------- fc1: st1 = st1g @ fc1_w + fc1_b ----------------
__global__ __launch_bounds__(256) void k_fc1s(
    const float* st1g, const float* fc1_w, const float* fc1_b, float* st1)
{
    int n0 = blockIdx.x*16, t = threadIdx.x;
    __shared__ float a_l[16*256];
    for (int i = t; i < 4096; i += 256) a_l[i] = st1g[i];
    __syncthreads();
    int nl = t & 15, b = t >> 4;
    float acc = fc1_b[n0+nl];
    #pragma unroll 16
    for (int k = 0; k < 256; ++k) acc += a_l[b*256+k]*fc1_w[k*256 + n0 + nl];
    st1[b*256 + n0 + nl] = acc;
}

// ---------------- K4: MFMA GEMM et = imgT @ ua_w + epilogue -> bf16 NHWC halo-padded ----------------
// Barrier-free: A-fragments straight from imgT (bf16, k-contiguous), B from uat.
// Grid (H, 2, B): n-half per block; wave n0 = ny*128 + wv*32; 12 acc frags.
__global__ __launch_bounds__(256) void k_et(
    const unsigned short* imgT, const unsigned short* uat, const float* ua_b,
    const float* st1, const float* att_sum, const float* uf_w, const float* uf_b,
    unsigned short* et_p)
{
    int h = blockIdx.x, ny = blockIdx.y, b = blockIdx.z;
    int t = threadIdx.x;
    int wv = t >> 6, lane = t & 63, q = lane >> 4, ln = lane & 15;
    int n0 = ny*128 + wv*32;

    f32x4 acc[12];                                          // [mf*2 + j]
    #pragma unroll
    for (int i = 0; i < 12; ++i) acc[i] = (f32x4){0.f,0.f,0.f,0.f};

    const unsigned short* abase = imgT + ((size_t)(b*HW) + h*W)*1024 + q*8;
    const unsigned short* bbase = uat + (size_t)(n0 + ln)*1024 + q*8;

    for (int c0 = 0; c0 < 1024; c0 += 32) {
        short8 av[6];
        #pragma unroll
        for (int mf = 0; mf < 6; ++mf)
            av[mf] = *(const short8*)(abase + (size_t)(ln + 16*mf)*1024 + c0);
        #pragma unroll
        for (int j = 0; j < 2; ++j) {
            short8 bv = *(const short8*)(bbase + (size_t)(j*16)*1024 + c0);
            #pragma unroll
            for (int mf = 0; mf < 6; ++mf)
                acc[mf*2+j] = __builtin_amdgcn_mfma_f32_16x16x32_bf16(av[mf], bv, acc[mf*2+j], 0, 0, 0);
        }
    }

    float att_m[24];
    #pragma unroll
    for (int mf = 0; mf < 6; ++mf)
        #pragma unroll
        for (int r = 0; r < 4; ++r)
            att_m[mf*4+r] = att_sum[(b*H + h)*W + mf*16 + q*4 + r];
    #pragma unroll
    for (int j = 0; j < 2; ++j) {
        int n = n0 + j*16 + ln;
        float s1 = st1[b*256 + n] + ua_b[n];
        float ufw = uf_w[n], ufb = uf_b[n];
        #pragma unroll
        for (int mf = 0; mf < 6; ++mf)
            #pragma unroll
            for (int r = 0; r < 4; ++r) {
                int m = mf*16 + q*4 + r;
                float v = acc[mf*2+j][r] + s1 + att_m[mf*4+r]*ufw + ufb;
                et_p[((size_t)(b*H2 + h + 1)*W2 + (m + 1))*256 + n] = f2bf(v);
            }
    }
}

// ---------------- K5: MFMA conv(3x3,256->256) + BN + tanh + v-dot -> e_part[ny][b,h,w] ----------------
// Barrier-free K-loop: A direct from halo-padded et_p (L1/L2), B from wtb. Grid (H, 2, B).
__global__ __launch_bounds__(256) void k_conv(
    const unsigned short* et_p, const unsigned short* wtb, const float* cb,
    const float* bn_g, const float* bn_b, const float* bn_m, const float* bn_v,
    const float* v_w, float* e_part)
{
    int h = blockIdx.x, ny = blockIdx.y, b = blockIdx.z;
    int t = threadIdx.x;
    int wv = t >> 6, lane = t & 63, q = lane >> 4, ln = lane & 15;
    int n0 = ny*128 + wv*32;
    __shared__ float lds_red[4][96];

    f32x4 acc[12];                                          // [mf*2 + j]
    #pragma unroll
    for (int i = 0; i < 12; ++i) acc[i] = (f32x4){0.f,0.f,0.f,0.f};

    #pragma unroll
    for (int kh = 0; kh < 3; ++kh) {
        #pragma unroll
        for (int kw = 0; kw < 3; ++kw) {
            const unsigned short* arow = et_p + ((size_t)(b*H2 + h + kh)*W2 + kw)*256 + q*8;
            const unsigned short* brow = wtb + ((size_t)((kh*3 + kw)*256 + n0 + ln))*256 + q*8;
            #pragma unroll 2
            for (int c0 = 0; c0 < 256; c0 += 32) {
                short8 av[6];
                #pragma unroll
                for (int mf = 0; mf < 6; ++mf)
                    av[mf] = *(const short8*)(arow + (size_t)(ln + 16*mf)*256 + c0);
                #pragma unroll
                for (int j = 0; j < 2; ++j) {
                    short8 bv = *(const short8*)(brow + (size_t)(j*16)*256 + c0);
                    #pragma unroll
                    for (int mf = 0; mf < 6; ++mf)
                        acc[mf*2+j] = __builtin_amdgcn_mfma_f32_16x16x32_bf16(av[mf], bv, acc[mf*2+j], 0, 0, 0);
                }
            }
        }
    }

    // epilogue: bias + BN + tanh + *v_w, reduce over this block's 128 o's
    float psum[24];
    #pragma unroll
    for (int i = 0; i < 24; ++i) psum[i] = 0.f;
    #pragma unroll
    for (int j = 0; j < 2; ++j) {
        int o = n0 + j*16 + ln;
        float inv  = bn_g[o]*rsqrtf(bn_v[o] + BN_EPS);
        float mean = bn_m[o], beta = bn_b[o], bias = cb[o], vw = v_w[o];
        #pragma unroll
        for (int mf = 0; mf < 6; ++mf)
            #pragma unroll
            for (int r = 0; r < 4; ++r) {
                float x = (acc[mf*2+j][r] + bias - mean)*inv + beta;
                x = fminf(fmaxf(x, -15.f), 15.f);
                float ex = __expf(2.f*x);
                psum[mf*4+r] += ((ex - 1.f)/(ex + 1.f))*vw;
            }
    }
    #pragma unroll
    for (int s = 1; s < 16; s <<= 1)
        #pragma unroll
        for (int i = 0; i < 24; ++i) psum[i] += __shfl_xor(psum[i], s);
    if (ln == 0) {
        #pragma unroll
        for (int mf = 0; mf < 6; ++mf)
            #pragma unroll
            for (int r = 0; r < 4; ++r)
                lds_red[wv][mf*16 + q*4 + r] = psum[mf*4+r];
    }
    __syncthreads();
    if (t < 96)
        e_part[(size_t)ny*(B*HW) + (b*H + h)*W + t] =
            lds_red[0][t] + lds_red[1][t] + lds_red[2][t] + lds_red[3][t];
}

// ---------------- K6: masked softmax over (h,w) -> alpha (sums the two e partials) ----------------
__global__ __launch_bounds__(256) void k_softmax(
    const float* e_part, const int* h_mask, const int* w_mask, const float* v_b,
    float* alpha_out)
{
    int b = blockIdx.x, t = threadIdx.x;
    int hm = h_mask[b], wm = w_mask[b];
    float vb = v_b[0];
    __shared__ float red[256];
    float vals[9];
    float loc = 0.f;
    #pragma unroll
    for (int i = 0; i < 9; ++i) {
        int hw = t + i*256;
        int hh = hw / W, ww = hw % W;
        float v = 0.f;
        if (hh < hm && ww < wm)
            v = __expf(e_part[b*HW + hw] + e_part[B*HW + b*HW + hw] + vb);
        vals[i] = v; loc += v;
    }
    red[t] = loc; __syncthreads();
    for (int s = 128; s > 0; s >>= 1) { if (t < s) red[t] += red[t+s]; __syncthreads(); }
    float inv = 1.f/(red[0] + 1e-8f);
    #pragma unroll
    for (int i = 0; i < 9; ++i) alpha_out[b*HW + t + i*256] = vals[i]*inv;
}

// ---------------- zero ct ----------------
__global__ __launch_bounds__(256) void k_ct0(float* ct)
{
    ct[blockIdx.x*256 + threadIdx.x] = 0.f;
}

// ---------------- K7: ct[b,c] += sum_hw alpha[b,hw]*imgT[b,hw,c] (bf16 A, fp32 acc, atomics) ----------------
__global__ __launch_bounds__(256) void k_ct(
    const float* alpha, const unsigned short* imgT, float* ct)
{
    int s = blockIdx.x, b = blockIdx.y, t = threadIdx.x;
    int cg = (t & 127)*8, half = t >> 7;
    float acc[8];
    #pragma unroll
    for (int j = 0; j < 8; ++j) acc[j] = 0.f;
    for (int i = 0; i < 96; ++i) {
        int hw = s*192 + i*2 + half;
        float a = alpha[b*HW + hw];
        union { short8 v; unsigned short u[8]; } pk;
        pk.v = *(const short8*)&imgT[((size_t)(b*HW) + hw)*1024 + cg];
        #pragma unroll
        for (int j = 0; j < 8; ++j) acc[j] += a*bf2f(pk.u[j]);
    }
    #pragma unroll
    for (int j = 0; j < 8; ++j) atomicAdd(&ct[b*1024 + cg + j], acc[j]);
}

// ---------------- GRU2 h-side + pemb: gh2[b][0:768]=st1@wh, [768:896]=emb@emb2_w ----------------
__global__ __launch_bounds__(256) void k_gh2pe(
    const float* st1, const int* y, const float* emb_table,
    const float* wh, const float* emb2_w, float* gh2)
{
    int virt = blockIdx.x*16, t = threadIdx.x;
    bool ghm = virt < 768;
    __shared__ float a_l[16*256];
    for (int i = t; i < 4096; i += 256) {
        int b = i >> 8, k = i & 255;
        a_l[i] = ghm ? st1[b*256 + k] : emb_table[y[b]*EMB + k];
    }
    __syncthreads();
    int nl = t & 15, b = t >> 4;
    float acc = 0.f;
    if (ghm) {
        int n = virt + nl;
        #pragma unroll 16
        for (int k = 0; k < 256; ++k) acc += a_l[b*256+k]*wh[k*768 + n];
    } else {
        int n = virt - 768 + nl;
        #pragma unroll 16
        for (int k = 0; k < 256; ++k) acc += a_l[b*256+k]*emb2_w[k*128 + n];
    }
    gh2[b*896 + virt + nl] = acc;
}

// ---------------- GRU2 i-side + wc (split-K) ----------------
__global__ __launch_bounds__(256) void k_gi2(
    const float* ct, const float* wi, const float* wc_w, float* gi2p)
{
    int virt = blockIdx.x*16, ks = blockIdx.y, t = threadIdx.x;
    int k0 = ks*256;
    __shared__ float a_l[16*256];
    for (int i = t; i < 4096; i += 256) {
        int b = i >> 8, k = i & 255;
        a_l[i] = ct[b*1024 + k0 + k];
    }
    __syncthreads();
    int nl = t & 15, b = t >> 4;
    float acc = 0.f;
    if (virt < 768) {
        int n = virt + nl;
        #pragma unroll 16
        for (int k = 0; k < 256; ++k) acc += a_l[b*256+k]*wi[(k0+k)*768 + n];
    } else {
        int n = virt - 768 + nl;
        #pragma unroll 16
        for (int k = 0; k < 256; ++k) acc += a_l[b*256+k]*wc_w[(k0+k)*128 + n];
    }
    gi2p[(ks*16 + b)*896 + virt + nl] = acc;
}

// ---------------- GRU2 nonlinearity -> st (+hidden out) ----------------
__global__ __launch_bounds__(256) void k_comb2(
    const float* gi2p, const float* gh2, const float* st1,
    const float* bi, const float* bh, float* hidden_out, float* st_ws)
{
    int b = blockIdx.x, t = threadIdx.x;
    float ir = bi[t], iz = bi[256+t], in_ = bi[512+t];
    #pragma unroll
    for (int ks = 0; ks < 4; ++ks) {
        const float* g = gi2p + (ks*16 + b)*896;
        ir += g[t]; iz += g[256+t]; in_ += g[512+t];
    }
    const float* gh = gh2 + b*896;
    float hr = gh[t] + bh[t], hz = gh[256+t] + bh[256+t], hn = gh[512+t] + bh[512+t];
    float h = st1[b*256+t];
    float r = 1.f/(1.f+__expf(-(ir+hr)));
    float z = 1.f/(1.f+__expf(-(iz+hz)));
    float n = tanhf(in_ + r*hn);
    float s = (1.f - z)*n + z*h;
    hidden_out[b*HID + t] = s;
    st_ws[b*256 + t] = s;
}

// ---------------- pre = st@fc2_w + fc2_b + pemb + emb2_b + wcp + wc_b ----------------
__global__ __launch_bounds__(256) void k_fc2s(
    const float* st_ws, const float* fc2_w, const float* fc2_b,
    const float* gh2, const float* emb2_b, const float* gi2p,
    const float* wc_b, float* pre)
{
    int n0 = blockIdx.x*16, t = threadIdx.x;
    __shared__ float a_l[16*256];
    for (int i = t; i < 4096; i += 256) a_l[i] = st_ws[i];
    __syncthreads();
    int nl = t & 15, b = t >> 4;
    int n = n0 + nl;
    float acc = fc2_b[n] + emb2_b[n] + wc_b[n] + gh2[b*896 + 768 + n];
    #pragma unroll
    for (int ks = 0; ks < 4; ++ks) acc += gi2p[(ks*16 + b)*896 + 768 + n];
    #pragma unroll 16
    for (int k = 0; k < 256; ++k) acc += a_l[b*256+k]*fc2_w[k*128 + n];
    pre[b*128 + n] = acc;
}

// ---------------- logits (raw) = pre @ out_w + out_b ----------------
__global__ __launch_bounds__(256) void k_logits(
    const float* pre, const float* out_w, const float* out_b, float* out)
{
    int j0 = blockIdx.x*64, t = threadIdx.x;
    __shared__ float pre_l[16*128];
    for (int i = t; i < 2048; i += 256) pre_l[i] = pre[i];
    __syncthreads();
    int jl = t & 63, bg = t >> 6;
    int j = j0 + jl;
    if (j >= V) return;
    float acc0=0.f, acc1=0.f, acc2=0.f, acc3=0.f;
    const float* pl = pre_l + bg*4*128;
    #pragma unroll 8
    for (int k = 0; k < 128; ++k) {
        float wv = out_w[k*V + j];
        acc0 += pl[k]*wv; acc1 += pl[128+k]*wv; acc2 += pl[256+k]*wv; acc3 += pl[384+k]*wv;
    }
    float ob = out_b[j];
    out[(bg*4+0)*V + j] = acc0 + ob;
    out[(bg*4+1)*V + j] = acc1 + ob;
    out[(bg*4+2)*V + j] = acc2 + ob;
    out[(bg*4+3)*V + j] = acc3 + ob;
}

// ---------------- in-place log_softmax over V per batch ----------------
__global__ __launch_bounds__(1024) void k_lsm(float* out)
{
    int b = blockIdx.x, t = threadIdx.x;
    __shared__ float red[1024];
    float lg[5]; float mx = -1e30f;
    #pragma unroll
    for (int i = 0; i < 5; ++i) {
        int j = t + i*1024;
        lg[i] = (j < V) ? out[b*V + j] : -1e30f;
        mx = fmaxf(mx, lg[i]);
    }
    red[t] = mx; __syncthreads();
    for (int s = 512; s > 0; s >>= 1) { if (t < s) red[t] = fmaxf(red[t], red[t+s]); __syncthreads(); }
    float gmax = red[0]; __syncthreads();
    float se = 0.f;
    #pragma unroll
    for (int i = 0; i < 5; ++i) { int j = t + i*1024; if (j < V) se += __expf(lg[i] - gmax); }
    red[t] = se; __syncthreads();
    for (int s = 512; s > 0; s >>= 1) { if (t < s) red[t] += red[t+s]; __syncthreads(); }
    float lse = logf(red[0]);
    #pragma unroll
    for (int i = 0; i < 5; ++i) { int j = t + i*1024; if (j < V) out[b*V + j] = lg[i] - gmax - lse; }
}

extern "C" void kernel_launch(void* const* d_in, const int* in_sizes, int n_in,
                              void* d_out, int out_size, void* d_ws, size_t ws_size,
                              hipStream_t stream)
{
    const int*   input_y      = (const int*)  d_in[0];
    const float* input_hidden = (const float*)d_in[1];
    const float* img          = (const float*)d_in[2];
    const float* attention    = (const float*)d_in[4];
    const float* alpha_t      = (const float*)d_in[5];
    const int*   h_mask       = (const int*)  d_in[8];
    const int*   w_mask       = (const int*)  d_in[9];
    const float* emb_table    = (const float*)d_in[10];
    const float* gru1_wi      = (const float*)d_in[11];
    const float* gru1_wh      = (const float*)d_in[12];
    const float* gru1_bi      = (const float*)d_in[13];
    const float* gru1_bh      = (const float*)d_in[14];
    const float* fc1_w        = (const float*)d_in[15];
    const float* fc1_b        = (const float*)d_in[16];
    const float* gru2_wi      = (const float*)d_in[17];
    const float* gru2_wh      = (const float*)d_in[18];
    const float* gru2_bi      = (const float*)d_in[19];
    const float* gru2_bh      = (const float*)d_in[20];
    const float* out_w        = (const float*)d_in[21];
    const float* out_b        = (const float*)d_in[22];
    const float* emb2_w       = (const float*)d_in[23];
    const float* emb2_b       = (const float*)d_in[24];
    const float* conv1_w      = (const float*)d_in[25];
    const float* conv1_b      = (const float*)d_in[26];
    const float* conv_tan_w   = (const float*)d_in[27];
    const float* conv_tan_b   = (const float*)d_in[28];
    const float* fc2_w        = (const float*)d_in[29];
    const float* fc2_b        = (const float*)d_in[30];
    const float* ua_w         = (const float*)d_in[31];
    const float* ua_b         = (const float*)d_in[32];
    const float* uf_w         = (const float*)d_in[33];
    const float* uf_b         = (const float*)d_in[34];
    const float* v_w          = (const float*)d_in[35];
    const float* v_b          = (const float*)d_in[36];
    const float* wc_w         = (const float*)d_in[37];
    const float* wc_b         = (const float*)d_in[38];
    const float* bn1_gamma    = (const float*)d_in[39];
    const float* bn1_beta     = (const float*)d_in[40];
    const float* bn1_mean     = (const float*)d_in[41];
    const float* bn1_var      = (const float*)d_in[42];

    float* out = (float*)d_out;
    char*  ws  = (char*)d_ws;
    unsigned short* imgT = (unsigned short*)(ws + WSB_IMGT);
    unsigned short* et_p = (unsigned short*)(ws + WSB_ETP);
    unsigned short* wtb  = (unsigned short*)(ws + WSB_WTB);
    unsigned short* uat  = (unsigned short*)(ws + WSB_UAT);
    float* e_part = (float*)(ws + WSB_E);
    float* st1   = (float*)(ws + WSB_ST1);
    float* ct    = (float*)(ws + WSB_CT);
    float* pre   = (float*)(ws + WSB_PRE);
    float* gigh1 = (float*)(ws + WSB_GIGH1);
    float* st1g  = (float*)(ws + WSB_ST1G);
    float* gh2   = (float*)(ws + WSB_GH2);
    float* gi2p  = (float*)(ws + WSB_GI2);
    float* st_w  = (float*)(ws + WSB_STW);

    float* out_logits = out + OUT0;
    float* out_hidden = out + OUT1;
    float* out_alpha  = out + OUT2;
    float* out_attsum = out + OUT3;

    k_imgT<<<dim3(HW/128, C/128, B), 256, 0, stream>>>(img, imgT);
    k_tail1<<<96, 256, 0, stream>>>(input_y, emb_table, input_hidden,
                                    gru1_wi, gru1_wh, gigh1);
    k_comb1<<<B, 256, 0, stream>>>(gigh1, input_hidden, gru1_bi, gru1_bh, st1g);
    k_fc1s<<<16, 256, 0, stream>>>(st1g, fc1_w, fc1_b, st1);
    k_attsum<<<(B*HW)/256, 256, 0, stream>>>(attention, alpha_t, conv1_w, conv1_b, out_attsum);
    k_wtb<<<(9*256*256)/256, 256, 0, stream>>>(conv_tan_w, wtb);
    k_uat<<<(256*1024)/256, 256, 0, stream>>>(ua_w, uat);
    k_zero<<<(B*H2*W2*256/8)/256, 256, 0, stream>>>((int4*)et_p);
    k_et<<<dim3(H, 2, B), 256, 0, stream>>>(imgT, uat, ua_b, st1, out_attsum,
                                            uf_w, uf_b, et_p);
    k_conv<<<dim3(H, 2, B), 256, 0, stream>>>(et_p, wtb, conv_tan_b,
                                              bn1_gamma, bn1_beta, bn1_mean, bn1_var,
                                              v_w, e_part);
    k_softmax<<<B, 256, 0, stream>>>(e_part, h_mask, w_mask, v_b, out_alpha);
    k_ct0<<<(B*C)/256, 256, 0, stream>>>(ct);
    k_ct<<<dim3(12, B), 256, 0, stream>>>(out_alpha, imgT, ct);
    k_gh2pe<<<56, 256, 0, stream>>>(st1, input_y, emb_table, gru2_wh, emb2_w, gh2);
    k_gi2<<<dim3(56, 4), 256, 0, stream>>>(ct, gru2_wi, wc_w, gi2p);
    k_comb2<<<B, 256, 0, stream>>>(gi2p, gh2, st1, gru2_bi, gru2_bh, out_hidden, st_w);
    k_fc2s<<<8, 256, 0, stream>>>(st_w, fc2_w, fc2_b, gh2, emb2_b, gi2p, wc_b, pre);
    k_logits<<<(V + 63)/64, 256, 0, stream>>>(pre, out_w, out_b, out_logits);
    k_lsm<<<B, 1024, 0, stream>>>(out_logits);
}

// Round 6
// 564.975 us; speedup vs baseline: 1.3055x; 1.3055x over previous
//
#include <hip/hip_runtime.h>
#include <hip/hip_bf16.h>

// Problem constants
#define B   16
#define H   24
#define W   96
#define C   1024
#define HID 256
#define V   5000
#define EMB 256
#define HW  (H*W)          // 2304
#define BN_EPS 1e-5f
#define H2  (H+2)          // 26 (halo-padded)
#define W2  (W+2)          // 98

// d_out layout (floats): output[B*V] | hidden[B*HID] | alpha[B*HW] | att_sum[B*HW]
#define OUT0 0
#define OUT1 (B*V)
#define OUT2 (OUT1 + B*HID)
#define OUT3 (OUT2 + B*HW)

// ws layout (bytes, 256-aligned)
#define WSB_IMGT  0                      // B*HW*C bf16      = 75,497,472
#define WSB_ETP   75497472               // B*H2*W2*256 bf16 = 20,873,216
#define WSB_WTB   96370688               // 9*256*256 bf16   =  1,179,648
#define WSB_UAT   97550336               // 256*1024 bf16    =    524,288
#define WSB_E     98074624               // 2*B*HW f32       =    294,912
#define WSB_ST1   98369536               // B*256 f32
#define WSB_CT    98385920               // B*1024 f32
#define WSB_PRE   98451456               // B*128 f32
#define WSB_GIGH1 98459648               // B*1536 f32
#define WSB_ST1G  98557952               // B*256 f32
#define WSB_GH2   98574336               // B*896 f32
#define WSB_GI2   98631680               // 4*B*896 f32
#define WSB_STW   98861056               // B*256 f32

typedef __attribute__((ext_vector_type(8))) short short8;
typedef __attribute__((ext_vector_type(4))) float f32x4;

__device__ inline unsigned short f2bf(float f) {
    union { float f; unsigned int u; } v; v.f = f;
    unsigned int r = v.u + 0x7fffu + ((v.u >> 16) & 1u);   // RNE
    return (unsigned short)(r >> 16);
}
__device__ inline float bf2f(unsigned short u) {
    union { unsigned int u; float f; } v; v.u = ((unsigned int)u) << 16;
    return v.f;
}

// ---------------- img fp32 [b][c][hw] -> bf16 [b][hw][c] (tiled LDS transpose) ----------------
__global__ __launch_bounds__(256) void k_imgT(const float* img, unsigned short* imgT)
{
    int hw0 = blockIdx.x*128, c1 = blockIdx.y*128, b = blockIdx.z;
    int t = threadIdx.x;
    __shared__ unsigned short tr[128*136];                  // [hw][c] pad->136
    #pragma unroll
    for (int i = 0; i < 16; ++i) {
        int flat = i*1024 + t*4;                            // 0..16383
        int r = flat >> 7;                                  // c-row
        int col = flat & 127;                               // hw-col
        float4 v = *(const float4*)&img[((size_t)(b*C + c1 + r))*HW + hw0 + col];
        tr[(col+0)*136 + r] = f2bf(v.x);
        tr[(col+1)*136 + r] = f2bf(v.y);
        tr[(col+2)*136 + r] = f2bf(v.z);
        tr[(col+3)*136 + r] = f2bf(v.w);
    }
    __syncthreads();
    #pragma unroll
    for (int i = 0; i < 8; ++i) {
        int flat = i*2048 + t*8;
        int orow = flat >> 7;                               // hw
        int oc = flat & 127;
        *(short8*)&imgT[((size_t)(b*HW) + hw0 + orow)*1024 + c1 + oc] =
            *(const short8*)&tr[orow*136 + oc];
    }
}

// ---------------- K2: 1-ch 3x3 conv on alpha_t + attention_sum -> att_sum ----------------
__global__ __launch_bounds__(256) void k_attsum(
    const float* att_in, const float* alpha_t, const float* cw, const float* cb,
    float* att_out)
{
    int i = blockIdx.x*256 + threadIdx.x;
    int w = i % W; int h = (i / W) % H; int b = i / HW;
    float s = cb[0];
    #pragma unroll
    for (int kh = 0; kh < 3; ++kh) {
        int r = h + kh - 1; if (r < 0 || r >= H) continue;
        #pragma unroll
        for (int kw = 0; kw < 3; ++kw) {
            int c = w + kw - 1; if (c < 0 || c >= W) continue;
            s += alpha_t[(b*H + r)*W + c]*cw[kh*3+kw];
        }
    }
    att_out[i] = att_in[i] + s;
}

// ---------------- K3: conv_tan_w OIHW -> bf16 [khw][o][c] ----------------
__global__ __launch_bounds__(256) void k_wtb(const float* src, unsigned short* dst)
{
    int idx = blockIdx.x*256 + threadIdx.x;     // 9*256*256
    int c = idx & 255; int o = (idx >> 8) & 255; int khw = idx >> 16;
    dst[(khw*256 + o)*256 + c] = f2bf(src[(o*256 + c)*9 + khw]);
}

// ---------------- K3b: ua_w [c][d] -> bf16 [d][c] ----------------
__global__ __launch_bounds__(256) void k_uat(const float* src, unsigned short* dst)
{
    int idx = blockIdx.x*256 + threadIdx.x;     // 256*1024
    int c = idx & 1023; int d = idx >> 10;
    dst[d*1024 + c] = f2bf(src[c*256 + d]);
}

// ---------------- K3c: zero et_p (incl. halo) ----------------
__global__ __launch_bounds__(256) void k_zero(int4* p)
{
    p[blockIdx.x*256 + threadIdx.x] = make_int4(0,0,0,0);
}

// ---------------- GRU1 matmuls: gigh[b][0:768]=emb@wi, [768:1536]=h0@wh ----------------
__global__ __launch_bounds__(256) void k_tail1(
    const int* y, const float* emb_table, const float* h0,
    const float* wi, const float* wh, float* gigh)
{
    int virt = blockIdx.x*16;            // 0..1535
    int t = threadIdx.x;
    bool gi_mode = virt < 768;
    __shared__ float a_l[16*256];
    for (int i = t; i < 4096; i += 256) {
        int b = i >> 8, k = i & 255;
        a_l[i] = gi_mode ? emb_table[y[b]*EMB + k] : h0[b*HID + k];
    }
    __syncthreads();
    int nl = t & 15, b = t >> 4;
    int n = (gi_mode ? virt : virt - 768) + nl;
    const float* wp = gi_mode ? wi : wh;
    float acc = 0.f;
    #pragma unroll 16
    for (int k = 0; k < 256; ++k) acc += a_l[b*256 + k]*wp[k*768 + n];
    gigh[b*1536 + virt + nl] = acc;
}

// ---------------- GRU1 nonlinearity -> st1g ----------------
__global__ __launch_bounds__(256) void k_comb1(
    const float* gigh, const float* h0, const float* bi, const float* bh, float* st1g)
{
    int b = blockIdx.x, t = threadIdx.x;
    const float* g = gigh + b*1536;
    float ir = g[t] + bi[t], iz = g[256+t] + bi[256+t], in_ = g[512+t] + bi[512+t];
    float hr = g[768+t] + bh[t], hz = g[1024+t] + bh[256+t], hn = g[1280+t] + bh[512+t];
    float r = 1.f/(1.f+__expf(-(ir+hr)));
    float z = 1.f/(1.f+__expf(-(iz+hz)));
    float n = tanhf(in_ + r*hn);
    st1g[b*256+t] = (1.f - z)*n + z*h0[b*HID + t];
}

// ---------------- fc1: st1 = st1g @ fc1_w + fc1_b ----------------
__global__ __launch_bounds__(256) void k_fc1s(
    const float* st1g, const float* fc1_w, const float* fc1_b, float* st1)
{
    int n0 = blockIdx.x*16, t = threadIdx.x;
    __shared__ float a_l[16*256];
    for (int i = t; i < 4096; i += 256) a_l[i] = st1g[i];
    __syncthreads();
    int nl = t & 15, b = t >> 4;
    float acc = fc1_b[n0+nl];
    #pragma unroll 16
    for (int k = 0; k < 256; ++k) acc += a_l[b*256+k]*fc1_w[k*256 + n0 + nl];
    st1[b*256 + n0 + nl] = acc;
}

// ---------------- K4: MFMA GEMM et = imgT @ ua_w + epilogue -> bf16 NHWC halo-padded ----------------
// Grid (H, 2, B); LDS-staged A (contiguous bf16 copy from imgT, 128-ch chunks);
// per wave: 6 m-frags x 2 n-frags = 12 acc; 48 MFMA between barrier pairs.
__global__ __launch_bounds__(256, 3) void k_et(
    const unsigned short* imgT, const unsigned short* uat, const float* ua_b,
    const float* st1, const float* att_sum, const float* uf_w, const float* uf_b,
    unsigned short* et_p)
{
    int h = blockIdx.x, ny = blockIdx.y, b = blockIdx.z;
    int t = threadIdx.x;
    int wv = t >> 6, lane = t & 63, q = lane >> 4, ln = lane & 15;
    int n0 = ny*128 + wv*32;
    __shared__ __align__(16) unsigned short a_l[96*136];    // [m][c] stride 136, 26.1 KB

    f32x4 acc[12];                                          // [mf*2 + j]
    #pragma unroll
    for (int i = 0; i < 12; ++i) acc[i] = (f32x4){0.f,0.f,0.f,0.f};

    const unsigned short* ab = imgT + ((size_t)(b*HW) + h*W)*1024;
    const unsigned short* bbase = uat + (size_t)(n0 + ln)*1024 + q*8;

    for (int c0 = 0; c0 < 1024; c0 += 128) {
        __syncthreads();
        // stage 96 rows x 128 ch: 1536 int4
        #pragma unroll
        for (int i = t; i < 1536; i += 256) {
            int m = i >> 4, j = i & 15;
            ((int4*)a_l)[m*17 + j] = *((const int4*)(ab + (size_t)m*1024 + c0) + j);
        }
        __syncthreads();
        #pragma unroll
        for (int cs = 0; cs < 128; cs += 32) {
            short8 av[6];
            #pragma unroll
            for (int mf = 0; mf < 6; ++mf)
                av[mf] = *(const short8*)&a_l[(ln + 16*mf)*136 + cs + q*8];
            #pragma unroll
            for (int j = 0; j < 2; ++j) {
                short8 bv = *(const short8*)(bbase + (size_t)(j*16)*1024 + c0 + cs);
                #pragma unroll
                for (int mf = 0; mf < 6; ++mf)
                    acc[mf*2+j] = __builtin_amdgcn_mfma_f32_16x16x32_bf16(av[mf], bv, acc[mf*2+j], 0, 0, 0);
            }
        }
    }

    float att_m[24];
    #pragma unroll
    for (int mf = 0; mf < 6; ++mf)
        #pragma unroll
        for (int r = 0; r < 4; ++r)
            att_m[mf*4+r] = att_sum[(b*H + h)*W + mf*16 + q*4 + r];
    #pragma unroll
    for (int j = 0; j < 2; ++j) {
        int n = n0 + j*16 + ln;
        float s1 = st1[b*256 + n] + ua_b[n];
        float ufw = uf_w[n], ufb = uf_b[n];
        #pragma unroll
        for (int mf = 0; mf < 6; ++mf)
            #pragma unroll
            for (int r = 0; r < 4; ++r) {
                int m = mf*16 + q*4 + r;
                float v = acc[mf*2+j][r] + s1 + att_m[mf*4+r]*ufw + ufb;
                et_p[((size_t)(b*H2 + h + 1)*W2 + (m + 1))*256 + n] = f2bf(v);
            }
    }
}

// ---------------- K5: MFMA conv(3x3,256->256) + BN + tanh + v-dot -> e_part[ny][b,h,w] ----------------
// Grid (H, 2, B); LDS-staged halo patch (64-ch chunks, stride-72);
// per wave: 12 acc; 216 MFMA between barrier pairs.
__global__ __launch_bounds__(256, 3) void k_conv(
    const unsigned short* et_p, const unsigned short* wtb, const float* cb,
    const float* bn_g, const float* bn_b, const float* bn_m, const float* bn_v,
    const float* v_w, float* e_part)
{
    int h = blockIdx.x, ny = blockIdx.y, b = blockIdx.z;
    int t = threadIdx.x;
    int wv = t >> 6, lane = t & 63, q = lane >> 4, ln = lane & 15;
    int n0 = ny*128 + wv*32;
    __shared__ __align__(16) unsigned short patch[3*98*72]; // 42.3 KB
    __shared__ float lds_red[4][96];

    f32x4 acc[12];                                          // [mf*2 + j]
    #pragma unroll
    for (int i = 0; i < 12; ++i) acc[i] = (f32x4){0.f,0.f,0.f,0.f};

    for (int c0 = 0; c0 < 256; c0 += 64) {
        __syncthreads();
        // stage 3 rows x 98 x-positions x 64 channels: 2352 int4
        for (int i = t; i < 2352; i += 256) {
            int kh = i / 784; int r = i - kh*784; int x = r >> 3; int j = r & 7;
            const int4* src = (const int4*)et_p + ((size_t)(b*H2 + h + kh)*W2 + x)*32 + (c0 >> 3) + j;
            ((int4*)patch)[kh*882 + x*9 + j] = *src;
        }
        __syncthreads();
        #pragma unroll
        for (int kh = 0; kh < 3; ++kh) {
            #pragma unroll
            for (int kw = 0; kw < 3; ++kw) {
                const unsigned short* brow = wtb + ((size_t)((kh*3 + kw)*256 + n0 + ln))*256 + c0 + q*8;
                #pragma unroll
                for (int cs = 0; cs < 64; cs += 32) {
                    short8 av[6];
                    #pragma unroll
                    for (int mf = 0; mf < 6; ++mf)
                        av[mf] = *(const short8*)&patch[kh*7056 + (ln + 16*mf + kw)*72 + cs + q*8];
                    #pragma unroll
                    for (int j = 0; j < 2; ++j) {
                        short8 bv = *(const short8*)(brow + j*4096 + cs);
                        #pragma unroll
                        for (int mf = 0; mf < 6; ++mf)
                            acc[mf*2+j] = __builtin_amdgcn_mfma_f32_16x16x32_bf16(av[mf], bv, acc[mf*2+j], 0, 0, 0);
                    }
                }
            }
        }
    }

    // epilogue: bias + BN + tanh + *v_w, reduce over this block's 128 o's
    float psum[24];
    #pragma unroll
    for (int i = 0; i < 24; ++i) psum[i] = 0.f;
    #pragma unroll
    for (int j = 0; j < 2; ++j) {
        int o = n0 + j*16 + ln;
        float inv  = bn_g[o]*rsqrtf(bn_v[o] + BN_EPS);
        float mean = bn_m[o], beta = bn_b[o], bias = cb[o], vw = v_w[o];
        #pragma unroll
        for (int mf = 0; mf < 6; ++mf)
            #pragma unroll
            for (int r = 0; r < 4; ++r) {
                float x = (acc[mf*2+j][r] + bias - mean)*inv + beta;
                x = fminf(fmaxf(x, -15.f), 15.f);
                float ex = __expf(2.f*x);
                psum[mf*4+r] += ((ex - 1.f)/(ex + 1.f))*vw;
            }
    }
    #pragma unroll
    for (int s = 1; s < 16; s <<= 1)
        #pragma unroll
        for (int i = 0; i < 24; ++i) psum[i] += __shfl_xor(psum[i], s);
    if (ln == 0) {
        #pragma unroll
        for (int mf = 0; mf < 6; ++mf)
            #pragma unroll
            for (int r = 0; r < 4; ++r)
                lds_red[wv][mf*16 + q*4 + r] = psum[mf*4+r];
    }
    __syncthreads();
    if (t < 96)
        e_part[(size_t)ny*(B*HW) + (b*H + h)*W + t] =
            lds_red[0][t] + lds_red[1][t] + lds_red[2][t] + lds_red[3][t];
}

// ---------------- K6: masked softmax over (h,w) -> alpha (sums the two e partials) ----------------
__global__ __launch_bounds__(256) void k_softmax(
    const float* e_part, const int* h_mask, const int* w_mask, const float* v_b,
    float* alpha_out)
{
    int b = blockIdx.x, t = threadIdx.x;
    int hm = h_mask[b], wm = w_mask[b];
    float vb = v_b[0];
    __shared__ float red[256];
    float vals[9];
    float loc = 0.f;
    #pragma unroll
    for (int i = 0; i < 9; ++i) {
        int hw = t + i*256;
        int hh = hw / W, ww = hw % W;
        float v = 0.f;
        if (hh < hm && ww < wm)
            v = __expf(e_part[b*HW + hw] + e_part[B*HW + b*HW + hw] + vb);
        vals[i] = v; loc += v;
    }
    red[t] = loc; __syncthreads();
    for (int s = 128; s > 0; s >>= 1) { if (t < s) red[t] += red[t+s]; __syncthreads(); }
    float inv = 1.f/(red[0] + 1e-8f);
    #pragma unroll
    for (int i = 0; i < 9; ++i) alpha_out[b*HW + t + i*256] = vals[i]*inv;
}

// ---------------- zero ct ----------------
__global__ __launch_bounds__(256) void k_ct0(float* ct)
{
    ct[blockIdx.x*256 + threadIdx.x] = 0.f;
}

// ---------------- K7: ct[b,c] += sum_hw alpha[b,hw]*imgT[b,hw,c] (bf16 A, fp32 acc, atomics) ----------------
__global__ __launch_bounds__(256) void k_ct(
    const float* alpha, const unsigned short* imgT, float* ct)
{
    int s = blockIdx.x, b = blockIdx.y, t = threadIdx.x;
    int cg = (t & 127)*8, half = t >> 7;
    float acc[8];
    #pragma unroll
    for (int j = 0; j < 8; ++j) acc[j] = 0.f;
    for (int i = 0; i < 96; ++i) {
        int hw = s*192 + i*2 + half;
        float a = alpha[b*HW + hw];
        union { short8 v; unsigned short u[8]; } pk;
        pk.v = *(const short8*)&imgT[((size_t)(b*HW) + hw)*1024 + cg];
        #pragma unroll
        for (int j = 0; j < 8; ++j) acc[j] += a*bf2f(pk.u[j]);
    }
    #pragma unroll
    for (int j = 0; j < 8; ++j) atomicAdd(&ct[b*1024 + cg + j], acc[j]);
}

// ---------------- GRU2 h-side + pemb: gh2[b][0:768]=st1@wh, [768:896]=emb@emb2_w ----------------
__global__ __launch_bounds__(256) void k_gh2pe(
    const float* st1, const int* y, const float* emb_table,
    const float* wh, const float* emb2_w, float* gh2)
{
    int virt = blockIdx.x*16, t = threadIdx.x;
    bool ghm = virt < 768;
    __shared__ float a_l[16*256];
    for (int i = t; i < 4096; i += 256) {
        int b = i >> 8, k = i & 255;
        a_l[i] = ghm ? st1[b*256 + k] : emb_table[y[b]*EMB + k];
    }
    __syncthreads();
    int nl = t & 15, b = t >> 4;
    float acc = 0.f;
    if (ghm) {
        int n = virt + nl;
        #pragma unroll 16
        for (int k = 0; k < 256; ++k) acc += a_l[b*256+k]*wh[k*768 + n];
    } else {
        int n = virt - 768 + nl;
        #pragma unroll 16
        for (int k = 0; k < 256; ++k) acc += a_l[b*256+k]*emb2_w[k*128 + n];
    }
    gh2[b*896 + virt + nl] = acc;
}

// ---------------- GRU2 i-side + wc (split-K) ----------------
__global__ __launch_bounds__(256) void k_gi2(
    const float* ct, const float* wi, const float* wc_w, float* gi2p)
{
    int virt = blockIdx.x*16, ks = blockIdx.y, t = threadIdx.x;
    int k0 = ks*256;
    __shared__ float a_l[16*256];
    for (int i = t; i < 4096; i += 256) {
        int b = i >> 8, k = i & 255;
        a_l[i] = ct[b*1024 + k0 + k];
    }
    __syncthreads();
    int nl = t & 15, b = t >> 4;
    float acc = 0.f;
    if (virt < 768) {
        int n = virt + nl;
        #pragma unroll 16
        for (int k = 0; k < 256; ++k) acc += a_l[b*256+k]*wi[(k0+k)*768 + n];
    } else {
        int n = virt - 768 + nl;
        #pragma unroll 16
        for (int k = 0; k < 256; ++k) acc += a_l[b*256+k]*wc_w[(k0+k)*128 + n];
    }
    gi2p[(ks*16 + b)*896 + virt + nl] = acc;
}

// ---------------- GRU2 nonlinearity -> st (+hidden out) ----------------
__global__ __launch_bounds__(256) void k_comb2(
    const float* gi2p, const float* gh2, const float* st1,
    const float* bi, const float* bh, float* hidden_out, float* st_ws)
{
    int b = blockIdx.x, t = threadIdx.x;
    float ir = bi[t], iz = bi[256+t], in_ = bi[512+t];
    #pragma unroll
    for (int ks = 0; ks < 4; ++ks) {
        const float* g = gi2p + (ks*16 + b)*896;
        ir += g[t]; iz += g[256+t]; in_ += g[512+t];
    }
    const float* gh = gh2 + b*896;
    float hr = gh[t] + bh[t], hz = gh[256+t] + bh[256+t], hn = gh[512+t] + bh[512+t];
    float h = st1[b*256+t];
    float r = 1.f/(1.f+__expf(-(ir+hr)));
    float z = 1.f/(1.f+__expf(-(iz+hz)));
    float n = tanhf(in_ + r*hn);
    float s = (1.f - z)*n + z*h;
    hidden_out[b*HID + t] = s;
    st_ws[b*256 + t] = s;
}

// ---------------- pre = st@fc2_w + fc2_b + pemb + emb2_b + wcp + wc_b ----------------
__global__ __launch_bounds__(256) void k_fc2s(
    const float* st_ws, const float* fc2_w, const float* fc2_b,
    const float* gh2, const float* emb2_b, const float* gi2p,
    const float* wc_b, float* pre)
{
    int n0 = blockIdx.x*16, t = threadIdx.x;
    __shared__ float a_l[16*256];
    for (int i = t; i < 4096; i += 256) a_l[i] = st_ws[i];
    __syncthreads();
    int nl = t & 15, b = t >> 4;
    int n = n0 + nl;
    float acc = fc2_b[n] + emb2_b[n] + wc_b[n] + gh2[b*896 + 768 + n];
    #pragma unroll
    for (int ks = 0; ks < 4; ++ks) acc += gi2p[(ks*16 + b)*896 + 768 + n];
    #pragma unroll 16
    for (int k = 0; k < 256; ++k) acc += a_l[b*256+k]*fc2_w[k*128 + n];
    pre[b*128 + n] = acc;
}

// ---------------- logits (raw) = pre @ out_w + out_b ----------------
__global__ __launch_bounds__(256) void k_logits(
    const float* pre, const float* out_w, const float* out_b, float* out)
{
    int j0 = blockIdx.x*64, t = threadIdx.x;
    __shared__ float pre_l[16*128];
    for (int i = t; i < 2048; i += 256) pre_l[i] = pre[i];
    __syncthreads();
    int jl = t & 63, bg = t >> 6;
    int j = j0 + jl;
    if (j >= V) return;
    float acc0=0.f, acc1=0.f, acc2=0.f, acc3=0.f;
    const float* pl = pre_l + bg*4*128;
    #pragma unroll 8
    for (int k = 0; k < 128; ++k) {
        float wv = out_w[k*V + j];
        acc0 += pl[k]*wv; acc1 += pl[128+k]*wv; acc2 += pl[256+k]*wv; acc3 += pl[384+k]*wv;
    }
    float ob = out_b[j];
    out[(bg*4+0)*V + j] = acc0 + ob;
    out[(bg*4+1)*V + j] = acc1 + ob;
    out[(bg*4+2)*V + j] = acc2 + ob;
    out[(bg*4+3)*V + j] = acc3 + ob;
}

// ---------------- in-place log_softmax over V per batch ----------------
__global__ __launch_bounds__(1024) void k_lsm(float* out)
{
    int b = blockIdx.x, t = threadIdx.x;
    __shared__ float red[1024];
    float lg[5]; float mx = -1e30f;
    #pragma unroll
    for (int i = 0; i < 5; ++i) {
        int j = t + i*1024;
        lg[i] = (j < V) ? out[b*V + j] : -1e30f;
        mx = fmaxf(mx, lg[i]);
    }
    red[t] = mx; __syncthreads();
    for (int s = 512; s > 0; s >>= 1) { if (t < s) red[t] = fmaxf(red[t], red[t+s]); __syncthreads(); }
    float gmax = red[0]; __syncthreads();
    float se = 0.f;
    #pragma unroll
    for (int i = 0; i < 5; ++i) { int j = t + i*1024; if (j < V) se += __expf(lg[i] - gmax); }
    red[t] = se; __syncthreads();
    for (int s = 512; s > 0; s >>= 1) { if (t < s) red[t] += red[t+s]; __syncthreads(); }
    float lse = logf(red[0]);
    #pragma unroll
    for (int i = 0; i < 5; ++i) { int j = t + i*1024; if (j < V) out[b*V + j] = lg[i] - gmax - lse; }
}

extern "C" void kernel_launch(void* const* d_in, const int* in_sizes, int n_in,
                              void* d_out, int out_size, void* d_ws, size_t ws_size,
                              hipStream_t stream)
{
    const int*   input_y      = (const int*)  d_in[0];
    const float* input_hidden = (const float*)d_in[1];
    const float* img          = (const float*)d_in[2];
    const float* attention    = (const float*)d_in[4];
    const float* alpha_t      = (const float*)d_in[5];
    const int*   h_mask       = (const int*)  d_in[8];
    const int*   w_mask       = (const int*)  d_in[9];
    const float* emb_table    = (const float*)d_in[10];
    const float* gru1_wi      = (const float*)d_in[11];
    const float* gru1_wh      = (const float*)d_in[12];
    const float* gru1_bi      = (const float*)d_in[13];
    const float* gru1_bh      = (const float*)d_in[14];
    const float* fc1_w        = (const float*)d_in[15];
    const float* fc1_b        = (const float*)d_in[16];
    const float* gru2_wi      = (const float*)d_in[17];
    const float* gru2_wh      = (const float*)d_in[18];
    const float* gru2_bi      = (const float*)d_in[19];
    const float* gru2_bh      = (const float*)d_in[20];
    const float* out_w        = (const float*)d_in[21];
    const float* out_b        = (const float*)d_in[22];
    const float* emb2_w       = (const float*)d_in[23];
    const float* emb2_b       = (const float*)d_in[24];
    const float* conv1_w      = (const float*)d_in[25];
    const float* conv1_b      = (const float*)d_in[26];
    const float* conv_tan_w   = (const float*)d_in[27];
    const float* conv_tan_b   = (const float*)d_in[28];
    const float* fc2_w        = (const float*)d_in[29];
    const float* fc2_b        = (const float*)d_in[30];
    const float* ua_w         = (const float*)d_in[31];
    const float* ua_b         = (const float*)d_in[32];
    const float* uf_w         = (const float*)d_in[33];
    const float* uf_b         = (const float*)d_in[34];
    const float* v_w          = (const float*)d_in[35];
    const float* v_b          = (const float*)d_in[36];
    const float* wc_w         = (const float*)d_in[37];
    const float* wc_b         = (const float*)d_in[38];
    const float* bn1_gamma    = (const float*)d_in[39];
    const float* bn1_beta     = (const float*)d_in[40];
    const float* bn1_mean     = (const float*)d_in[41];
    const float* bn1_var      = (const float*)d_in[42];

    float* out = (float*)d_out;
    char*  ws  = (char*)d_ws;
    unsigned short* imgT = (unsigned short*)(ws + WSB_IMGT);
    unsigned short* et_p = (unsigned short*)(ws + WSB_ETP);
    unsigned short* wtb  = (unsigned short*)(ws + WSB_WTB);
    unsigned short* uat  = (unsigned short*)(ws + WSB_UAT);
    float* e_part = (float*)(ws + WSB_E);
    float* st1   = (float*)(ws + WSB_ST1);
    float* ct    = (float*)(ws + WSB_CT);
    float* pre   = (float*)(ws + WSB_PRE);
    float* gigh1 = (float*)(ws + WSB_GIGH1);
    float* st1g  = (float*)(ws + WSB_ST1G);
    float* gh2   = (float*)(ws + WSB_GH2);
    float* gi2p  = (float*)(ws + WSB_GI2);
    float* st_w  = (float*)(ws + WSB_STW);

    float* out_logits = out + OUT0;
    float* out_hidden = out + OUT1;
    float* out_alpha  = out + OUT2;
    float* out_attsum = out + OUT3;

    k_imgT<<<dim3(HW/128, C/128, B), 256, 0, stream>>>(img, imgT);
    k_tail1<<<96, 256, 0, stream>>>(input_y, emb_table, input_hidden,
                                    gru1_wi, gru1_wh, gigh1);
    k_comb1<<<B, 256, 0, stream>>>(gigh1, input_hidden, gru1_bi, gru1_bh, st1g);
    k_fc1s<<<16, 256, 0, stream>>>(st1g, fc1_w, fc1_b, st1);
    k_attsum<<<(B*HW)/256, 256, 0, stream>>>(attention, alpha_t, conv1_w, conv1_b, out_attsum);
    k_wtb<<<(9*256*256)/256, 256, 0, stream>>>(conv_tan_w, wtb);
    k_uat<<<(256*1024)/256, 256, 0, stream>>>(ua_w, uat);
    k_zero<<<(B*H2*W2*256/8)/256, 256, 0, stream>>>((int4*)et_p);
    k_et<<<dim3(H, 2, B), 256, 0, stream>>>(imgT, uat, ua_b, st1, out_attsum,
                                            uf_w, uf_b, et_p);
    k_conv<<<dim3(H, 2, B), 256, 0, stream>>>(et_p, wtb, conv_tan_b,
                                              bn1_gamma, bn1_beta, bn1_mean, bn1_var,
                                              v_w, e_part);
    k_softmax<<<B, 256, 0, stream>>>(e_part, h_mask, w_mask, v_b, out_alpha);
    k_ct0<<<(B*C)/256, 256, 0, stream>>>(ct);
    k_ct<<<dim3(12, B), 256, 0, stream>>>(out_alpha, imgT, ct);
    k_gh2pe<<<56, 256, 0, stream>>>(st1, input_y, emb_table, gru2_wh, emb2_w, gh2);
    k_gi2<<<dim3(56, 4), 256, 0, stream>>>(ct, gru2_wi, wc_w, gi2p);
    k_comb2<<<B, 256, 0, stream>>>(gi2p, gh2, st1, gru2_bi, gru2_bh, out_hidden, st_w);
    k_fc2s<<<8, 256, 0, stream>>>(st_w, fc2_w, fc2_b, gh2, emb2_b, gi2p, wc_b, pre);
    k_logits<<<(V + 63)/64, 256, 0, stream>>>(pre, out_w, out_b, out_logits);
    k_lsm<<<B, 1024, 0, stream>>>(out_logits);
}

// Round 7
// 549.499 us; speedup vs baseline: 1.3423x; 1.0282x over previous
//
#include <hip/hip_runtime.h>
#include <hip/hip_bf16.h>

// Problem constants
#define B   16
#define H   24
#define W   96
#define C   1024
#define HID 256
#define V   5000
#define EMB 256
#define HW  (H*W)          // 2304
#define BN_EPS 1e-5f
#define H2  (H+2)          // 26 (halo-padded)
#define W2  (W+2)          // 98

// d_out layout (floats): output[B*V] | hidden[B*HID] | alpha[B*HW] | att_sum[B*HW]
#define OUT0 0
#define OUT1 (B*V)
#define OUT2 (OUT1 + B*HID)
#define OUT3 (OUT2 + B*HW)

// ws layout (bytes, 256-aligned)
#define WSB_IMGT  0                      // B*HW*C bf16      = 75,497,472
#define WSB_ETP   75497472               // B*H2*W2*256 bf16 = 20,873,216
#define WSB_WTB   96370688               // 9*256*256 bf16   =  1,179,648
#define WSB_UAT   97550336               // 256*1024 bf16    =    524,288
#define WSB_E     98074624               // 2*B*HW f32       =    294,912
#define WSB_ST1   98369536               // B*256 f32
#define WSB_CT    98385920               // B*1024 f32
#define WSB_PRE   98451456               // B*128 f32
#define WSB_GIGH1 98459648               // B*1536 f32
#define WSB_GH2   98574336               // B*896 f32
#define WSB_GI2   98631680               // 4*B*896 f32

typedef __attribute__((ext_vector_type(8))) short short8;
typedef __attribute__((ext_vector_type(4))) float f32x4;

__device__ inline unsigned short f2bf(float f) {
    union { float f; unsigned int u; } v; v.f = f;
    unsigned int r = v.u + 0x7fffu + ((v.u >> 16) & 1u);   // RNE
    return (unsigned short)(r >> 16);
}
__device__ inline float bf2f(unsigned short u) {
    union { unsigned int u; float f; } v; v.u = ((unsigned int)u) << 16;
    return v.f;
}

// ---------------- img fp32 [b][c][hw] -> bf16 [b][hw][c] (tiled LDS transpose) ----------------
__global__ __launch_bounds__(256) void k_imgT(const float* img, unsigned short* imgT)
{
    int hw0 = blockIdx.x*128, c1 = blockIdx.y*128, b = blockIdx.z;
    int t = threadIdx.x;
    __shared__ unsigned short tr[128*136];                  // [hw][c] pad->136
    #pragma unroll
    for (int i = 0; i < 16; ++i) {
        int flat = i*1024 + t*4;                            // 0..16383
        int r = flat >> 7;                                  // c-row
        int col = flat & 127;                               // hw-col
        float4 v = *(const float4*)&img[((size_t)(b*C + c1 + r))*HW + hw0 + col];
        tr[(col+0)*136 + r] = f2bf(v.x);
        tr[(col+1)*136 + r] = f2bf(v.y);
        tr[(col+2)*136 + r] = f2bf(v.z);
        tr[(col+3)*136 + r] = f2bf(v.w);
    }
    __syncthreads();
    #pragma unroll
    for (int i = 0; i < 8; ++i) {
        int flat = i*2048 + t*8;
        int orow = flat >> 7;                               // hw
        int oc = flat & 127;
        *(short8*)&imgT[((size_t)(b*HW) + hw0 + orow)*1024 + c1 + oc] =
            *(const short8*)&tr[orow*136 + oc];
    }
}

// ---------------- k_prep: fused wtb-transpose | uat-transpose | attsum-conv | ct-zero | et_p halo-zero ----------------
// grid partition: [0,2304) wtb; [2304,3328) uat; [3328,3472) attsum; [3472,3536) ct0; [3536,4024) halo
__global__ __launch_bounds__(256) void k_prep(
    const float* conv_w_src, unsigned short* wtb,
    const float* ua_w, unsigned short* uat,
    const float* att_in, const float* alpha_t, const float* cw, const float* cb, float* att_out,
    float* ct, unsigned short* et_p)
{
    int x = blockIdx.x, t = threadIdx.x;
    if (x < 2304) {
        int idx = x*256 + t;                                // 9*256*256
        int c = idx & 255; int o = (idx >> 8) & 255; int khw = idx >> 16;
        wtb[(khw*256 + o)*256 + c] = f2bf(conv_w_src[(o*256 + c)*9 + khw]);
    } else if (x < 3328) {
        int idx = (x - 2304)*256 + t;                       // 256*1024
        int c = idx & 1023; int d = idx >> 10;
        uat[d*1024 + c] = f2bf(ua_w[c*256 + d]);
    } else if (x < 3472) {
        int i = (x - 3328)*256 + t;                         // B*HW
        int w = i % W; int h = (i / W) % H; int b = i / HW;
        float s = cb[0];
        #pragma unroll
        for (int kh = 0; kh < 3; ++kh) {
            int r = h + kh - 1; if (r < 0 || r >= H) continue;
            #pragma unroll
            for (int kw = 0; kw < 3; ++kw) {
                int c = w + kw - 1; if (c < 0 || c >= W) continue;
                s += alpha_t[(b*H + r)*W + c]*cw[kh*3+kw];
            }
        }
        att_out[i] = att_in[i] + s;
    } else if (x < 3536) {
        ct[(x - 3472)*256 + t] = 0.f;                       // B*C
    } else {
        // halo zero: 7808 int4 per b (row0: 3136, row25: 3136, side cols: 1536)
        int flat = (x - 3536)*256 + t;                      // < 124928
        int b = flat / 7808; int r = flat - b*7808;
        int h2, w2, j;
        if (r < 3136)      { h2 = 0;  w2 = r >> 5;          j = r & 31; }
        else if (r < 6272) { h2 = 25; w2 = (r - 3136) >> 5; j = (r - 3136) & 31; }
        else {
            int rr = r - 6272;                              // < 1536
            h2 = 1 + (rr >> 6);
            int s = rr & 63;
            w2 = (s < 32) ? 0 : 97;
            j = s & 31;
        }
        ((int4*)et_p)[((size_t)(b*H2 + h2)*W2 + w2)*32 + j] = make_int4(0,0,0,0);
    }
}

// ---------------- GRU1 matmuls: gigh[b][0:768]=emb@wi, [768:1536]=h0@wh ----------------
__global__ __launch_bounds__(256) void k_tail1(
    const int* y, const float* emb_table, const float* h0,
    const float* wi, const float* wh, float* gigh)
{
    int virt = blockIdx.x*16;            // 0..1535
    int t = threadIdx.x;
    bool gi_mode = virt < 768;
    __shared__ float a_l[16*256];
    for (int i = t; i < 4096; i += 256) {
        int b = i >> 8, k = i & 255;
        a_l[i] = gi_mode ? emb_table[y[b]*EMB + k] : h0[b*HID + k];
    }
    __syncthreads();
    int nl = t & 15, b = t >> 4;
    int n = (gi_mode ? virt : virt - 768) + nl;
    const float* wp = gi_mode ? wi : wh;
    float acc = 0.f;
    #pragma unroll 16
    for (int k = 0; k < 256; ++k) acc += a_l[b*256 + k]*wp[k*768 + n];
    gigh[b*1536 + virt + nl] = acc;
}

// ---------------- k_fc1c: GRU1 nonlinearity (in-block) + fc1 -> st1 ----------------
__global__ __launch_bounds__(256) void k_fc1c(
    const float* gigh, const float* h0, const float* bi, const float* bh,
    const float* fc1_w, const float* fc1_b, float* st1)
{
    int n0 = blockIdx.x*16, t = threadIdx.x;
    __shared__ float a_l[16*256];
    for (int i = t; i < 4096; i += 256) {
        int b = i >> 8, k = i & 255;
        const float* g = gigh + b*1536;
        float ir = g[k] + bi[k], iz = g[256+k] + bi[256+k], in_ = g[512+k] + bi[512+k];
        float hr = g[768+k] + bh[k], hz = g[1024+k] + bh[256+k], hn = g[1280+k] + bh[512+k];
        float r = 1.f/(1.f+__expf(-(ir+hr)));
        float z = 1.f/(1.f+__expf(-(iz+hz)));
        float n = tanhf(in_ + r*hn);
        a_l[i] = (1.f - z)*n + z*h0[b*HID + k];
    }
    __syncthreads();
    int nl = t & 15, b = t >> 4;
    float acc = fc1_b[n0+nl];
    #pragma unroll 16
    for (int k = 0; k < 256; ++k) acc += a_l[b*256+k]*fc1_w[k*256 + n0 + nl];
    st1[b*256 + n0 + nl] = acc;
}

// ---------------- K4: MFMA GEMM et = imgT @ ua_w + epilogue -> bf16 NHWC halo-padded ----------------
__global__ __launch_bounds__(256, 3) void k_et(
    const unsigned short* imgT, const unsigned short* uat, const float* ua_b,
    const float* st1, const float* att_sum, const float* uf_w, const float* uf_b,
    unsigned short* et_p)
{
    int h = blockIdx.x, ny = blockIdx.y, b = blockIdx.z;
    int t = threadIdx.x;
    int wv = t >> 6, lane = t & 63, q = lane >> 4, ln = lane & 15;
    int n0 = ny*128 + wv*32;
    __shared__ __align__(16) unsigned short a_l[96*136];    // [m][c] stride 136, 26.1 KB

    f32x4 acc[12];                                          // [mf*2 + j]
    #pragma unroll
    for (int i = 0; i < 12; ++i) acc[i] = (f32x4){0.f,0.f,0.f,0.f};

    const unsigned short* ab = imgT + ((size_t)(b*HW) + h*W)*1024;
    const unsigned short* bbase = uat + (size_t)(n0 + ln)*1024 + q*8;

    for (int c0 = 0; c0 < 1024; c0 += 128) {
        __syncthreads();
        #pragma unroll
        for (int i = t; i < 1536; i += 256) {
            int m = i >> 4, j = i & 15;
            ((int4*)a_l)[m*17 + j] = *((const int4*)(ab + (size_t)m*1024 + c0) + j);
        }
        __syncthreads();
        #pragma unroll
        for (int cs = 0; cs < 128; cs += 32) {
            short8 av[6];
            #pragma unroll
            for (int mf = 0; mf < 6; ++mf)
                av[mf] = *(const short8*)&a_l[(ln + 16*mf)*136 + cs + q*8];
            #pragma unroll
            for (int j = 0; j < 2; ++j) {
                short8 bv = *(const short8*)(bbase + (size_t)(j*16)*1024 + c0 + cs);
                #pragma unroll
                for (int mf = 0; mf < 6; ++mf)
                    acc[mf*2+j] = __builtin_amdgcn_mfma_f32_16x16x32_bf16(av[mf], bv, acc[mf*2+j], 0, 0, 0);
            }
        }
    }

    float att_m[24];
    #pragma unroll
    for (int mf = 0; mf < 6; ++mf)
        #pragma unroll
        for (int r = 0; r < 4; ++r)
            att_m[mf*4+r] = att_sum[(b*H + h)*W + mf*16 + q*4 + r];
    #pragma unroll
    for (int j = 0; j < 2; ++j) {
        int n = n0 + j*16 + ln;
        float s1 = st1[b*256 + n] + ua_b[n];
        float ufw = uf_w[n], ufb = uf_b[n];
        #pragma unroll
        for (int mf = 0; mf < 6; ++mf)
            #pragma unroll
            for (int r = 0; r < 4; ++r) {
                int m = mf*16 + q*4 + r;
                float v = acc[mf*2+j][r] + s1 + att_m[mf*4+r]*ufw + ufb;
                et_p[((size_t)(b*H2 + h + 1)*W2 + (m + 1))*256 + n] = f2bf(v);
            }
    }
}

// ---------------- K5: MFMA conv(3x3,256->256) + BN + tanh + v-dot -> e_part[ny][b,h,w] ----------------
__global__ __launch_bounds__(256, 3) void k_conv(
    const unsigned short* et_p, const unsigned short* wtb, const float* cb,
    const float* bn_g, const float* bn_b, const float* bn_m, const float* bn_v,
    const float* v_w, float* e_part)
{
    int h = blockIdx.x, ny = blockIdx.y, b = blockIdx.z;
    int t = threadIdx.x;
    int wv = t >> 6, lane = t & 63, q = lane >> 4, ln = lane & 15;
    int n0 = ny*128 + wv*32;
    __shared__ __align__(16) unsigned short patch[3*98*72]; // 42.3 KB
    __shared__ float lds_red[4][96];

    f32x4 acc[12];                                          // [mf*2 + j]
    #pragma unroll
    for (int i = 0; i < 12; ++i) acc[i] = (f32x4){0.f,0.f,0.f,0.f};

    for (int c0 = 0; c0 < 256; c0 += 64) {
        __syncthreads();
        for (int i = t; i < 2352; i += 256) {
            int kh = i / 784; int r = i - kh*784; int x = r >> 3; int j = r & 7;
            const int4* src = (const int4*)et_p + ((size_t)(b*H2 + h + kh)*W2 + x)*32 + (c0 >> 3) + j;
            ((int4*)patch)[kh*882 + x*9 + j] = *src;
        }
        __syncthreads();
        #pragma unroll
        for (int kh = 0; kh < 3; ++kh) {
            #pragma unroll
            for (int kw = 0; kw < 3; ++kw) {
                const unsigned short* brow = wtb + ((size_t)((kh*3 + kw)*256 + n0 + ln))*256 + c0 + q*8;
                #pragma unroll
                for (int cs = 0; cs < 64; cs += 32) {
                    short8 av[6];
                    #pragma unroll
                    for (int mf = 0; mf < 6; ++mf)
                        av[mf] = *(const short8*)&patch[kh*7056 + (ln + 16*mf + kw)*72 + cs + q*8];
                    #pragma unroll
                    for (int j = 0; j < 2; ++j) {
                        short8 bv = *(const short8*)(brow + j*4096 + cs);
                        #pragma unroll
                        for (int mf = 0; mf < 6; ++mf)
                            acc[mf*2+j] = __builtin_amdgcn_mfma_f32_16x16x32_bf16(av[mf], bv, acc[mf*2+j], 0, 0, 0);
                    }
                }
            }
        }
    }

    float psum[24];
    #pragma unroll
    for (int i = 0; i < 24; ++i) psum[i] = 0.f;
    #pragma unroll
    for (int j = 0; j < 2; ++j) {
        int o = n0 + j*16 + ln;
        float inv  = bn_g[o]*rsqrtf(bn_v[o] + BN_EPS);
        float mean = bn_m[o], beta = bn_b[o], bias = cb[o], vw = v_w[o];
        #pragma unroll
        for (int mf = 0; mf < 6; ++mf)
            #pragma unroll
            for (int r = 0; r < 4; ++r) {
                float x = (acc[mf*2+j][r] + bias - mean)*inv + beta;
                x = fminf(fmaxf(x, -15.f), 15.f);
                float ex = __expf(2.f*x);
                psum[mf*4+r] += ((ex - 1.f)/(ex + 1.f))*vw;
            }
    }
    #pragma unroll
    for (int s = 1; s < 16; s <<= 1)
        #pragma unroll
        for (int i = 0; i < 24; ++i) psum[i] += __shfl_xor(psum[i], s);
    if (ln == 0) {
        #pragma unroll
        for (int mf = 0; mf < 6; ++mf)
            #pragma unroll
            for (int r = 0; r < 4; ++r)
                lds_red[wv][mf*16 + q*4 + r] = psum[mf*4+r];
    }
    __syncthreads();
    if (t < 96)
        e_part[(size_t)ny*(B*HW) + (b*H + h)*W + t] =
            lds_red[0][t] + lds_red[1][t] + lds_red[2][t] + lds_red[3][t];
}

// ---------------- K6: masked softmax over (h,w) -> alpha (sums the two e partials) ----------------
__global__ __launch_bounds__(256) void k_softmax(
    const float* e_part, const int* h_mask, const int* w_mask, const float* v_b,
    float* alpha_out)
{
    int b = blockIdx.x, t = threadIdx.x;
    int hm = h_mask[b], wm = w_mask[b];
    float vb = v_b[0];
    __shared__ float red[256];
    float vals[9];
    float loc = 0.f;
    #pragma unroll
    for (int i = 0; i < 9; ++i) {
        int hw = t + i*256;
        int hh = hw / W, ww = hw % W;
        float v = 0.f;
        if (hh < hm && ww < wm)
            v = __expf(e_part[b*HW + hw] + e_part[B*HW + b*HW + hw] + vb);
        vals[i] = v; loc += v;
    }
    red[t] = loc; __syncthreads();
    for (int s = 128; s > 0; s >>= 1) { if (t < s) red[t] += red[t+s]; __syncthreads(); }
    float inv = 1.f/(red[0] + 1e-8f);
    #pragma unroll
    for (int i = 0; i < 9; ++i) alpha_out[b*HW + t + i*256] = vals[i]*inv;
}

// ---------------- K7: ct[b,c] += sum_hw alpha[b,hw]*imgT[b,hw,c] (bf16 A, fp32 acc, atomics) ----------------
__global__ __launch_bounds__(256) void k_ct(
    const float* alpha, const unsigned short* imgT, float* ct)
{
    int s = blockIdx.x, b = blockIdx.y, t = threadIdx.x;
    int cg = (t & 127)*8, half = t >> 7;
    float acc[8];
    #pragma unroll
    for (int j = 0; j < 8; ++j) acc[j] = 0.f;
    for (int i = 0; i < 96; ++i) {
        int hw = s*192 + i*2 + half;
        float a = alpha[b*HW + hw];
        union { short8 v; unsigned short u[8]; } pk;
        pk.v = *(const short8*)&imgT[((size_t)(b*HW) + hw)*1024 + cg];
        #pragma unroll
        for (int j = 0; j < 8; ++j) acc[j] += a*bf2f(pk.u[j]);
    }
    #pragma unroll
    for (int j = 0; j < 8; ++j) atomicAdd(&ct[b*1024 + cg + j], acc[j]);
}

// ---------------- k_g2: fused GRU2 h-side+pemb | GRU2 i-side+wc (split-K) ----------------
// grid: [0,56) gh2pe; [56,280) gi2 (ks = (x-56)/56, virt = ((x-56)%56)*16)
__global__ __launch_bounds__(256) void k_g2(
    const float* st1, const int* y, const float* emb_table,
    const float* wh, const float* emb2_w, float* gh2,
    const float* ct, const float* wi, const float* wc_w, float* gi2p)
{
    int x = blockIdx.x, t = threadIdx.x;
    __shared__ float a_l[16*256];
    if (x < 56) {
        int virt = x*16;
        bool ghm = virt < 768;
        for (int i = t; i < 4096; i += 256) {
            int b = i >> 8, k = i & 255;
            a_l[i] = ghm ? st1[b*256 + k] : emb_table[y[b]*EMB + k];
        }
        __syncthreads();
        int nl = t & 15, b = t >> 4;
        float acc = 0.f;
        if (ghm) {
            int n = virt + nl;
            #pragma unroll 16
            for (int k = 0; k < 256; ++k) acc += a_l[b*256+k]*wh[k*768 + n];
        } else {
            int n = virt - 768 + nl;
            #pragma unroll 16
            for (int k = 0; k < 256; ++k) acc += a_l[b*256+k]*emb2_w[k*128 + n];
        }
        gh2[b*896 + virt + nl] = acc;
    } else {
        int xx = x - 56;
        int ks = xx / 56, virt = (xx - ks*56)*16;
        int k0 = ks*256;
        for (int i = t; i < 4096; i += 256) {
            int b = i >> 8, k = i & 255;
            a_l[i] = ct[b*1024 + k0 + k];
        }
        __syncthreads();
        int nl = t & 15, b = t >> 4;
        float acc = 0.f;
        if (virt < 768) {
            int n = virt + nl;
            #pragma unroll 16
            for (int k = 0; k < 256; ++k) acc += a_l[b*256+k]*wi[(k0+k)*768 + n];
        } else {
            int n = virt - 768 + nl;
            #pragma unroll 16
            for (int k = 0; k < 256; ++k) acc += a_l[b*256+k]*wc_w[(k0+k)*128 + n];
        }
        gi2p[(ks*16 + b)*896 + virt + nl] = acc;
    }
}

// ---------------- k_fc2c: GRU2 nonlinearity (in-block) + hidden write + pre ----------------
__global__ __launch_bounds__(256) void k_fc2c(
    const float* gi2p, const float* gh2, const float* st1,
    const float* bi, const float* bh,
    const float* fc2_w, const float* fc2_b, const float* emb2_b, const float* wc_b,
    float* hidden_out, float* pre)
{
    int n0 = blockIdx.x*16, t = threadIdx.x;
    __shared__ float st_l[16*256];
    for (int i = t; i < 4096; i += 256) {
        int b = i >> 8, k = i & 255;
        float ir = bi[k], iz = bi[256+k], in_ = bi[512+k];
        #pragma unroll
        for (int ks = 0; ks < 4; ++ks) {
            const float* g = gi2p + (ks*16 + b)*896;
            ir += g[k]; iz += g[256+k]; in_ += g[512+k];
        }
        const float* gh = gh2 + b*896;
        float hr = gh[k] + bh[k], hz = gh[256+k] + bh[256+k], hn = gh[512+k] + bh[512+k];
        float h = st1[b*256+k];
        float r = 1.f/(1.f+__expf(-(ir+hr)));
        float z = 1.f/(1.f+__expf(-(iz+hz)));
        float n = tanhf(in_ + r*hn);
        float s = (1.f - z)*n + z*h;
        st_l[i] = s;
        if (blockIdx.x == 0) hidden_out[b*HID + k] = s;
    }
    __syncthreads();
    int nl = t & 15, b = t >> 4;
    int n = n0 + nl;
    float acc = fc2_b[n] + emb2_b[n] + wc_b[n] + gh2[b*896 + 768 + n];
    #pragma unroll
    for (int ks = 0; ks < 4; ++ks) acc += gi2p[(ks*16 + b)*896 + 768 + n];
    #pragma unroll 16
    for (int k = 0; k < 256; ++k) acc += st_l[b*256+k]*fc2_w[k*128 + n];
    pre[b*128 + n] = acc;
}

// ---------------- logits (raw) = pre @ out_w + out_b ----------------
__global__ __launch_bounds__(256) void k_logits(
    const float* pre, const float* out_w, const float* out_b, float* out)
{
    int j0 = blockIdx.x*64, t = threadIdx.x;
    __shared__ float pre_l[16*128];
    for (int i = t; i < 2048; i += 256) pre_l[i] = pre[i];
    __syncthreads();
    int jl = t & 63, bg = t >> 6;
    int j = j0 + jl;
    if (j >= V) return;
    float acc0=0.f, acc1=0.f, acc2=0.f, acc3=0.f;
    const float* pl = pre_l + bg*4*128;
    #pragma unroll 8
    for (int k = 0; k < 128; ++k) {
        float wv = out_w[k*V + j];
        acc0 += pl[k]*wv; acc1 += pl[128+k]*wv; acc2 += pl[256+k]*wv; acc3 += pl[384+k]*wv;
    }
    float ob = out_b[j];
    out[(bg*4+0)*V + j] = acc0 + ob;
    out[(bg*4+1)*V + j] = acc1 + ob;
    out[(bg*4+2)*V + j] = acc2 + ob;
    out[(bg*4+3)*V + j] = acc3 + ob;
}

// ---------------- in-place log_softmax over V per batch ----------------
__global__ __launch_bounds__(1024) void k_lsm(float* out)
{
    int b = blockIdx.x, t = threadIdx.x;
    __shared__ float red[1024];
    float lg[5]; float mx = -1e30f;
    #pragma unroll
    for (int i = 0; i < 5; ++i) {
        int j = t + i*1024;
        lg[i] = (j < V) ? out[b*V + j] : -1e30f;
        mx = fmaxf(mx, lg[i]);
    }
    red[t] = mx; __syncthreads();
    for (int s = 512; s > 0; s >>= 1) { if (t < s) red[t] = fmaxf(red[t], red[t+s]); __syncthreads(); }
    float gmax = red[0]; __syncthreads();
    float se = 0.f;
    #pragma unroll
    for (int i = 0; i < 5; ++i) { int j = t + i*1024; if (j < V) se += __expf(lg[i] - gmax); }
    red[t] = se; __syncthreads();
    for (int s = 512; s > 0; s >>= 1) { if (t < s) red[t] += red[t+s]; __syncthreads(); }
    float lse = logf(red[0]);
    #pragma unroll
    for (int i = 0; i < 5; ++i) { int j = t + i*1024; if (j < V) out[b*V + j] = lg[i] - gmax - lse; }
}

extern "C" void kernel_launch(void* const* d_in, const int* in_sizes, int n_in,
                              void* d_out, int out_size, void* d_ws, size_t ws_size,
                              hipStream_t stream)
{
    const int*   input_y      = (const int*)  d_in[0];
    const float* input_hidden = (const float*)d_in[1];
    const float* img          = (const float*)d_in[2];
    const float* attention    = (const float*)d_in[4];
    const float* alpha_t      = (const float*)d_in[5];
    const int*   h_mask       = (const int*)  d_in[8];
    const int*   w_mask       = (const int*)  d_in[9];
    const float* emb_table    = (const float*)d_in[10];
    const float* gru1_wi      = (const float*)d_in[11];
    const float* gru1_wh      = (const float*)d_in[12];
    const float* gru1_bi      = (const float*)d_in[13];
    const float* gru1_bh      = (const float*)d_in[14];
    const float* fc1_w        = (const float*)d_in[15];
    const float* fc1_b        = (const float*)d_in[16];
    const float* gru2_wi      = (const float*)d_in[17];
    const float* gru2_wh      = (const float*)d_in[18];
    const float* gru2_bi      = (const float*)d_in[19];
    const float* gru2_bh      = (const float*)d_in[20];
    const float* out_w        = (const float*)d_in[21];
    const float* out_b        = (const float*)d_in[22];
    const float* emb2_w       = (const float*)d_in[23];
    const float* emb2_b       = (const float*)d_in[24];
    const float* conv1_w      = (const float*)d_in[25];
    const float* conv1_b      = (const float*)d_in[26];
    const float* conv_tan_w   = (const float*)d_in[27];
    const float* conv_tan_b   = (const float*)d_in[28];
    const float* fc2_w        = (const float*)d_in[29];
    const float* fc2_b        = (const float*)d_in[30];
    const float* ua_w         = (const float*)d_in[31];
    const float* ua_b         = (const float*)d_in[32];
    const float* uf_w         = (const float*)d_in[33];
    const float* uf_b         = (const float*)d_in[34];
    const float* v_w          = (const float*)d_in[35];
    const float* v_b          = (const float*)d_in[36];
    const float* wc_w         = (const float*)d_in[37];
    const float* wc_b         = (const float*)d_in[38];
    const float* bn1_gamma    = (const float*)d_in[39];
    const float* bn1_beta     = (const float*)d_in[40];
    const float* bn1_mean     = (const float*)d_in[41];
    const float* bn1_var      = (const float*)d_in[42];

    float* out = (float*)d_out;
    char*  ws  = (char*)d_ws;
    unsigned short* imgT = (unsigned short*)(ws + WSB_IMGT);
    unsigned short* et_p = (unsigned short*)(ws + WSB_ETP);
    unsigned short* wtb  = (unsigned short*)(ws + WSB_WTB);
    unsigned short* uat  = (unsigned short*)(ws + WSB_UAT);
    float* e_part = (float*)(ws + WSB_E);
    float* st1   = (float*)(ws + WSB_ST1);
    float* ct    = (float*)(ws + WSB_CT);
    float* pre   = (float*)(ws + WSB_PRE);
    float* gigh1 = (float*)(ws + WSB_GIGH1);
    float* gh2   = (float*)(ws + WSB_GH2);
    float* gi2p  = (float*)(ws + WSB_GI2);

    float* out_logits = out + OUT0;
    float* out_hidden = out + OUT1;
    float* out_alpha  = out + OUT2;
    float* out_attsum = out + OUT3;

    k_imgT<<<dim3(HW/128, C/128, B), 256, 0, stream>>>(img, imgT);
    k_prep<<<4024, 256, 0, stream>>>(conv_tan_w, wtb, ua_w, uat,
                                     attention, alpha_t, conv1_w, conv1_b, out_attsum,
                                     ct, et_p);
    k_tail1<<<96, 256, 0, stream>>>(input_y, emb_table, input_hidden,
                                    gru1_wi, gru1_wh, gigh1);
    k_fc1c<<<16, 256, 0, stream>>>(gigh1, input_hidden, gru1_bi, gru1_bh,
                                   fc1_w, fc1_b, st1);
    k_et<<<dim3(H, 2, B), 256, 0, stream>>>(imgT, uat, ua_b, st1, out_attsum,
                                            uf_w, uf_b, et_p);
    k_conv<<<dim3(H, 2, B), 256, 0, stream>>>(et_p, wtb, conv_tan_b,
                                              bn1_gamma, bn1_beta, bn1_mean, bn1_var,
                                              v_w, e_part);
    k_softmax<<<B, 256, 0, stream>>>(e_part, h_mask, w_mask, v_b, out_alpha);
    k_ct<<<dim3(12, B), 256, 0, stream>>>(out_alpha, imgT, ct);
    k_g2<<<280, 256, 0, stream>>>(st1, input_y, emb_table, gru2_wh, emb2_w, gh2,
                                  ct, gru2_wi, wc_w, gi2p);
    k_fc2c<<<8, 256, 0, stream>>>(gi2p, gh2, st1, gru2_bi, gru2_bh,
                                  fc2_w, fc2_b, emb2_b, wc_b, out_hidden, pre);
    k_logits<<<(V + 63)/64, 256, 0, stream>>>(pre, out_w, out_b, out_logits);
    k_lsm<<<B, 1024, 0, stream>>>(out_logits);
}